// Round 9
// baseline (1221.218 us; speedup 1.0000x reference)
//
#include <hip/hip_runtime.h>
#include <hip/hip_bf16.h>

#define T_DIM 512
#define H_DIM 4096
#define F_DIM 14336
#define KSEG  4   // split-K segments for down GEMM (14336/4 = 3584 = 56 x 64)

typedef __fp16 f16x8 __attribute__((ext_vector_type(8)));
typedef __fp16 f16x2 __attribute__((ext_vector_type(2)));
typedef float f32x4 __attribute__((ext_vector_type(4)));

// Barrier waiting only on LDS ops (lgkmcnt(0), vmcnt(63)): global register
// prefetch stays in flight across it. imm 0xC07F.
__device__ __forceinline__ void barrier_lgkm() {
    __asm__ __volatile__("" ::: "memory");
    __builtin_amdgcn_s_waitcnt(0xC07F);
    __builtin_amdgcn_s_barrier();
    __asm__ __volatile__("" ::: "memory");
}

// Zero d_out (harness poisons with 0xAA; down_kernel accumulates via atomics).
__global__ __launch_bounds__(256) void zero_out(float4* __restrict__ out) {
    out[blockIdx.x * 256 + threadIdx.x] = make_float4(0.f, 0.f, 0.f, 0.f);
}

// X fp32 -> f16 once.
__global__ __launch_bounds__(256) void cvt_x(const float* __restrict__ X,
                                             _Float16* __restrict__ Xh) {
    int i = (blockIdx.x * 256 + threadIdx.x) * 4;
    float4 v = *(const float4*)&X[i];
    union { struct { f16x2 a, b; } p; uint2 u; } u;
    u.p.a = __builtin_amdgcn_cvt_pkrtz(v.x, v.y);
    u.p.b = __builtin_amdgcn_cvt_pkrtz(v.z, v.w);
    *(uint2*)&Xh[i] = u.u;
}

// Dequant 4 int32 HQQ values -> 4 f16 (packed RTZ converts).
__device__ __forceinline__ ushort4 dq4(int4 qv, float s, float nzs) {
    union { struct { f16x2 lo, hi; } h; ushort4 u; } u;
    u.h.lo = __builtin_amdgcn_cvt_pkrtz(fmaf((float)qv.x, s, nzs),
                                        fmaf((float)qv.y, s, nzs));
    u.h.hi = __builtin_amdgcn_cvt_pkrtz(fmaf((float)qv.z, s, nzs),
                                        fmaf((float)qv.w, s, nzs));
    return u.u;
}

// ---------------------------------------------------------------------------
// G = silu(X@W1^T) * (X@W3^T) -> f16 [T,F]
// Single-barrier double-buffered pipeline (R8) + weight-only 32-VGPR
// prefetch (R4 discipline; R3/R8 showed 48 live prefetch regs -> scratch
// spill, 531 MB of WRITE traffic). X is L2/L3-resident -> sync load in
// the stage phase; its latency overlaps dequant + sibling wave's MFMA.
// Tile M128 x N64 x K64(=GROUP). 4 waves: wave&1 = m-half, wave>>1 = matrix.
// Grid: flat 896, XCD-swizzled. LDS 2 x 36864 = 73728 B -> 2 blocks/CU.
// ---------------------------------------------------------------------------
__global__ __launch_bounds__(256, 2)
void gate_up_kernel(const _Float16* __restrict__ Xh,
                    const int* __restrict__ W1q, const float* __restrict__ sc1,
                    const float* __restrict__ zp1,
                    const int* __restrict__ W3q, const float* __restrict__ sc3,
                    const float* __restrict__ zp3,
                    _Float16* __restrict__ G)
{
    constexpr int LK = 72;  // f16 elems/row: 144 B stride, 16B-aligned
    // per buf: rows 0..127 = X, 128..191 = W1, 192..255 = W3
    __shared__ __align__(16) unsigned short smem[2][256 * LK];

    const int t = threadIdx.x, wave = t >> 6, lane = t & 63;
    const int r = lane & 15, q = lane >> 4;
    const int mh = (wave & 1) * 64, mat = wave >> 1;

    const int b = blockIdx.x;
    const int xcd = b & 7, lb = b >> 3;         // lb in [0,112)
    const int m0 = (lb & 3) * 128;
    const int n0 = (xcd * 28 + (lb >> 2)) * 64; // n-tile in [0,224)
    const int SG = H_DIM / 64;

    const int xrow = t >> 3, xch = (t & 7) * 8;   // X: rows xrow+32i, 16B chunk
    const int wrow = t >> 4, wc = (t & 15) * 4;   // W: rows wrow+16i, 4 int32

    int4 rW1[4], rW3[4];   // ONLY live-across-barrier prefetch state (32 VGPRs)

    auto load_w = [&](int k0) {
        #pragma unroll
        for (int i = 0; i < 4; ++i) {
            size_t off = (size_t)(n0 + wrow + 16 * i) * H_DIM + k0 + wc;
            rW1[i] = *(const int4*)&W1q[off];
            rW3[i] = *(const int4*)&W3q[off];
        }
    };
    // stage tile (X sync-loaded here; W from prefetched regs)
    auto stage = [&](unsigned short* buf, int k0) {
        unsigned short* sX  = buf;
        unsigned short* sW1 = buf + 128 * LK;
        unsigned short* sW3 = buf + 192 * LK;
        const int gidx = k0 >> 6;
        int4 xv[4];
        #pragma unroll
        for (int i = 0; i < 4; ++i)
            xv[i] = *(const int4*)&Xh[(size_t)(m0 + xrow + 32 * i) * H_DIM + k0 + xch];
        #pragma unroll
        for (int i = 0; i < 4; ++i) {
            int row = wrow + 16 * i;
            int sidx = (n0 + row) * SG + gidx;
            float s = sc1[sidx], nzs = -zp1[sidx] * s;
            *(ushort4*)&sW1[row * LK + wc] = dq4(rW1[i], s, nzs);
            s = sc3[sidx]; nzs = -zp3[sidx] * s;
            *(ushort4*)&sW3[row * LK + wc] = dq4(rW3[i], s, nzs);
        }
        #pragma unroll
        for (int i = 0; i < 4; ++i)
            *(int4*)&sX[(xrow + 32 * i) * LK + xch] = xv[i];
    };

    f32x4 acc[4][4];
    #pragma unroll
    for (int a = 0; a < 4; ++a)
        #pragma unroll
        for (int c = 0; c < 4; ++c) acc[a][c] = (f32x4){0.f, 0.f, 0.f, 0.f};

    // prologue: W(tile0)->regs, stage tile0->buf0, W(tile1)->regs
    load_w(0);
    stage(smem[0], 0);
    load_w(64);
    barrier_lgkm();

    int p = 0;
    for (int k0 = 0; k0 < H_DIM; k0 += 64) {
        // MFMA on buf[p] (tile k0) — issued first, fills the matrix pipe
        const unsigned short* sX = smem[p];
        const unsigned short* sB = smem[p] + (mat ? 192 * LK : 128 * LK);
        #pragma unroll
        for (int kh = 0; kh < 2; ++kh) {
            const int kb = kh * 32 + q * 8;
            f16x8 av[4], bv[4];
            #pragma unroll
            for (int im = 0; im < 4; ++im)
                av[im] = *(const f16x8*)&sX[(mh + im * 16 + r) * LK + kb];
            #pragma unroll
            for (int j = 0; j < 4; ++j)
                bv[j] = *(const f16x8*)&sB[(j * 16 + r) * LK + kb];
            #pragma unroll
            for (int im = 0; im < 4; ++im)
                #pragma unroll
                for (int j = 0; j < 4; ++j)
                    acc[im][j] = __builtin_amdgcn_mfma_f32_16x16x32_f16(av[im], bv[j], acc[im][j], 0, 0, 0);
        }
        // stage tile k0+64 (consumes W regs); then prefetch W for k0+128
        int k1 = k0 + 64;
        if (k1 < H_DIM) {
            stage(smem[p ^ 1], k1);
            if (k1 + 64 < H_DIM) load_w(k1 + 64);
            barrier_lgkm();
        }
        p ^= 1;
    }

    // ---- epilogue: W3 waves -> smem[0] (last MFMA read smem[1]; disjoint);
    // one barrier; W1 waves combine+store ----
    float* sEx = (float*)&smem[0][0];  // 128 x 65 floats = 33280 B
    if (mat == 1) {
        #pragma unroll
        for (int im = 0; im < 4; ++im)
            #pragma unroll
            for (int j = 0; j < 4; ++j)
                #pragma unroll
                for (int reg = 0; reg < 4; ++reg)
                    sEx[(mh + im * 16 + q * 4 + reg) * 65 + j * 16 + r] = acc[im][j][reg];
    }
    __syncthreads();
    if (mat == 0) {
        #pragma unroll
        for (int im = 0; im < 4; ++im)
            #pragma unroll
            for (int j = 0; j < 4; ++j)
                #pragma unroll
                for (int reg = 0; reg < 4; ++reg) {
                    int ml = mh + im * 16 + q * 4 + reg;
                    int nl = j * 16 + r;
                    float g1 = acc[im][j][reg];
                    float g3 = sEx[ml * 65 + nl];
                    float val = g1 / (1.f + __expf(-g1)) * g3;
                    G[(size_t)(m0 + ml) * F_DIM + n0 + nl] = (_Float16)val;
                }
    }
}

// ---------------------------------------------------------------------------
// out += G @ W2^T (split-K, fp32 atomics). Same single-barrier double-buffer,
// W2-only prefetch (32 VGPRs); G sync-loaded (L3-resident, 14.7 MB).
// Tile M128 x N128 x K64, 4 waves x 64x64. Grid: flat 512 = 8 XCD x
// (4 m x 4 n x 4 kseg) -> exactly 2 blocks/CU. LDS 73728 B.
// ---------------------------------------------------------------------------
__global__ __launch_bounds__(256, 2)
void down_kernel(const _Float16* __restrict__ G,
                 const int* __restrict__ W2q, const float* __restrict__ sc2,
                 const float* __restrict__ zp2,
                 float* __restrict__ Out)
{
    constexpr int LK = 72;
    // per buf: rows 0..127 = A (G), 128..255 = W2
    __shared__ __align__(16) unsigned short smem[2][256 * LK];

    const int t = threadIdx.x, wave = t >> 6, lane = t & 63;
    const int r = lane & 15, q = lane >> 4;
    const int wm = (wave & 1) * 64, wn = (wave >> 1) * 64;

    const int b = blockIdx.x;
    const int xcd = b & 7, lb = b >> 3;          // lb in [0,64)
    const int m0 = (lb & 3) * 128;
    const int rest = lb >> 2;                    // [0,16)
    const int n0 = (xcd * 4 + (rest & 3)) * 128; // 32 n-tiles
    const int kbeg = (rest >> 2) * (F_DIM / KSEG);
    const int kend = kbeg + (F_DIM / KSEG);
    const int SG = F_DIM / 64;

    const int arow = t >> 3, ach = (t & 7) * 8;
    const int wrow = t >> 4, wc = (t & 15) * 4;

    int4 rW[8];   // W2-only prefetch (32 VGPRs)

    auto load_w = [&](int k0) {
        #pragma unroll
        for (int i = 0; i < 8; ++i)
            rW[i] = *(const int4*)&W2q[(size_t)(n0 + wrow + 16 * i) * F_DIM + k0 + wc];
    };
    auto stage = [&](unsigned short* buf, int k0) {
        unsigned short* sA = buf;
        unsigned short* sW = buf + 128 * LK;
        const int gidx = k0 >> 6;
        int4 gv[4];
        #pragma unroll
        for (int i = 0; i < 4; ++i)
            gv[i] = *(const int4*)&G[(size_t)(m0 + arow + 32 * i) * F_DIM + k0 + ach];
        #pragma unroll
        for (int i = 0; i < 8; ++i) {
            int row = wrow + 16 * i;
            int sidx = (n0 + row) * SG + gidx;
            float s = sc2[sidx], nzs = -zp2[sidx] * s;
            *(ushort4*)&sW[row * LK + wc] = dq4(rW[i], s, nzs);
        }
        #pragma unroll
        for (int i = 0; i < 4; ++i)
            *(int4*)&sA[(arow + 32 * i) * LK + ach] = gv[i];
    };

    f32x4 acc[4][4];
    #pragma unroll
    for (int a = 0; a < 4; ++a)
        #pragma unroll
        for (int c = 0; c < 4; ++c) acc[a][c] = (f32x4){0.f, 0.f, 0.f, 0.f};

    load_w(kbeg);
    stage(smem[0], kbeg);
    load_w(kbeg + 64);
    barrier_lgkm();

    int p = 0;
    for (int k0 = kbeg; k0 < kend; k0 += 64) {
        const unsigned short* sA = smem[p];
        const unsigned short* sW = smem[p] + 128 * LK;
        #pragma unroll
        for (int kh = 0; kh < 2; ++kh) {
            const int kb = kh * 32 + q * 8;
            f16x8 av[4], bv[4];
            #pragma unroll
            for (int im = 0; im < 4; ++im)
                av[im] = *(const f16x8*)&sA[(wm + im * 16 + r) * LK + kb];
            #pragma unroll
            for (int j = 0; j < 4; ++j)
                bv[j] = *(const f16x8*)&sW[(wn + j * 16 + r) * LK + kb];
            #pragma unroll
            for (int im = 0; im < 4; ++im)
                #pragma unroll
                for (int j = 0; j < 4; ++j)
                    acc[im][j] = __builtin_amdgcn_mfma_f32_16x16x32_f16(av[im], bv[j], acc[im][j], 0, 0, 0);
        }
        int k1 = k0 + 64;
        if (k1 < kend) {
            stage(smem[p ^ 1], k1);
            if (k1 + 64 < kend) load_w(k1 + 64);
            barrier_lgkm();
        }
        p ^= 1;
    }

    #pragma unroll
    for (int im = 0; im < 4; ++im)
        #pragma unroll
        for (int j = 0; j < 4; ++j)
            #pragma unroll
            for (int reg = 0; reg < 4; ++reg) {
                int m = m0 + wm + im * 16 + q * 4 + reg;
                int h = n0 + wn + j * 16 + r;
                atomicAdd(&Out[(size_t)m * H_DIM + h], acc[im][j][reg]);
            }
}

extern "C" void kernel_launch(void* const* d_in, const int* in_sizes, int n_in,
                              void* d_out, int out_size, void* d_ws, size_t ws_size,
                              hipStream_t stream) {
    const float* X   = (const float*)d_in[0];
    const int*   W1q = (const int*)d_in[1];
    const float* s1  = (const float*)d_in[2];
    const float* z1  = (const float*)d_in[3];
    const int*   W3q = (const int*)d_in[4];
    const float* s3  = (const float*)d_in[5];
    const float* z3  = (const float*)d_in[6];
    const int*   W2q = (const int*)d_in[7];
    const float* s2  = (const float*)d_in[8];
    const float* z2  = (const float*)d_in[9];
    float* Out = (float*)d_out;

    _Float16* Xh = (_Float16*)d_ws;                       // 4 MB
    _Float16* G  = (_Float16*)((char*)d_ws + (4 << 20));  // 14.7 MB

    zero_out<<<2048, 256, 0, stream>>>((float4*)Out);
    cvt_x<<<2048, 256, 0, stream>>>(X, Xh);
    gate_up_kernel<<<896, 256, 0, stream>>>(Xh, W1q, s1, z1, W3q, s3, z3, G);
    down_kernel<<<512, 256, 0, stream>>>(G, W2q, s2, z2, Out);
}